// Round 17
// baseline (70.917 us; speedup 1.0000x reference)
//
#include <hip/hip_runtime.h>
#include <hip/hip_bf16.h>

#define BB 16
#define SS 512
#define HH 1024

typedef __attribute__((ext_vector_type(4))) float f32x4;
typedef __attribute__((ext_vector_type(8))) short bhalf8;

static __device__ __forceinline__ unsigned int pack2(float a, float b) {
    __hip_bfloat162 h = __float22bfloat162_rn(make_float2(a, b));
    union { __hip_bfloat162 h; unsigned int u; } cv;
    cv.h = h;
    return cv.u;
}

static __device__ __forceinline__ unsigned short bf16u(float f) {
    union { float f; unsigned int u; } c; c.f = f;
    unsigned int r = c.u + 0x7FFFu + ((c.u >> 16) & 1u);   // RNE
    return (unsigned short)(r >> 16);
}

static __device__ __forceinline__ float ubf16(unsigned short u) {
    union { unsigned int u; float f; } c; c.u = ((unsigned int)u) << 16;
    return c.f;
}

// ---------------------------------------------------------------------------
// Prepass (all coalesced):
//   blocks [0,2048):    W[e][k][d] -> Wt2[e][ks][d][32k] bf16 via LDS transpose
//                       (Wt2 bf16 index: (e<<20) + ks*32768 + d*32 + k_in_32)
//   blocks [2048,6144): hid f32 -> hidb bf16
// ---------------------------------------------------------------------------
__global__ __launch_bounds__(256)
void prep_kernel(const float* __restrict__ W, const float* __restrict__ hid,
                 const int* __restrict__ eidx, unsigned short* __restrict__ Wt2,
                 unsigned short* __restrict__ hidb)
{
    int bid = blockIdx.x;
    int t = threadIdx.x;
    if (bid < 2048) {
        __shared__ float lds[32 * 132];
        int e  = bid >> 8;
        bool used = false;
        for (int b = 0; b < BB; ++b) used = used || (eidx[b] == e);
        if (!used) return;
        int rem = bid & 255;
        int kt = rem >> 3, dt = rem & 7;     // 32-k x 128-d tile
#pragma unroll
        for (int i = 0; i < 4; ++i) {
            int idx = t + i * 256;
            int row = idx >> 5, col4 = idx & 31;
            float4 v = *(const float4*)(W + ((size_t)e << 20)
                        + (size_t)(kt * 32 + row) * HH + dt * 128 + col4 * 4);
            float* dst = &lds[row * 132 + col4 * 4];
            dst[0] = v.x; dst[1] = v.y; dst[2] = v.z; dst[3] = v.w;
        }
        __syncthreads();
        int d = t >> 1, kh = t & 1;          // d 0..127, k-half (16 k each)
        unsigned int u[8];
#pragma unroll
        for (int p = 0; p < 8; ++p) {
            float a = lds[(kh * 16 + p * 2)     * 132 + d];
            float b = lds[(kh * 16 + p * 2 + 1) * 132 + d];
            u[p] = pack2(a, b);
        }
        unsigned short* dst = Wt2 + ((size_t)e << 20)
                            + (size_t)kt * 32768 + (size_t)(dt * 128 + d) * 32 + kh * 16;
        *reinterpret_cast<uint4*>(dst)     = make_uint4(u[0], u[1], u[2], u[3]);
        *reinterpret_cast<uint4*>(dst + 8) = make_uint4(u[4], u[5], u[6], u[7]);
    } else {
        int bid2 = bid - 2048;               // 2 rows per block
        int r = bid2 * 2 + (t >> 7);
        int col = (t & 127) * 8;
        const float* src = hid + (size_t)r * HH + col;
        float4 v0 = *(const float4*)(src);
        float4 v1 = *(const float4*)(src + 4);
        uint4 o;
        o.x = pack2(v0.x, v0.y); o.y = pack2(v0.z, v0.w);
        o.z = pack2(v1.x, v1.y); o.w = pack2(v1.z, v1.w);
        *reinterpret_cast<uint4*>(hidb + (size_t)r * HH + col) = o;
    }
}

// ---------------------------------------------------------------------------
// PURE GEMM, W-from-L2-direct: y = hid @ W[e] (bf16 store).
// 512 blocks x 512 thr (8 waves, 4m x 2n of 32x64), tile 128x128, BK=32.
// A: quad-buffered LDS (32KB total) via global_load_lds, pair-line XOR layout
//    (verified 0 conflicts). W: NO LDS — direct global->register bhalf8 loads
//    from Wt2 (contiguous 1KB per wave-load, L2-resident per XCD), 1-iter
//    register prefetch (bf/bfp). Per iter {2 ds_read; 4 W-loads(ks+1);
//    stageA(ks+3); s_barrier; setprio+8 MFMA; vmcnt(6); s_barrier}.
// ---------------------------------------------------------------------------
__global__ __launch_bounds__(512, 4)
void gemm8_kernel(const unsigned short* __restrict__ hidb,
                  const int* __restrict__ eidx,
                  const unsigned short* __restrict__ Wt2,
                  unsigned short* __restrict__ ybuf)
{
    __shared__ char ldsA[4 * 8192];    // A: bf16 [128 r][32 k] per buf

    int bx  = blockIdx.x;
    int swz = (bx & 7) * 64 + (bx >> 3);      // XCD-bijective (512 % 8 == 0)
    int bt   = swz >> 5;                      // batch 0..15
    int tile = swz & 31;
    int mt = tile >> 3, nt = tile & 7;        // 4 m-tiles x 8 n-tiles
    int e = eidx[bt];

    int t = threadIdx.x, wave = t >> 6, lane = t & 63;
    int l15 = lane & 15, g = lane >> 4;
    int wm = wave >> 1, wn = wave & 1;        // 4m x 2n, wave tile 32x64

    int brow = bt * SS + mt * 128;
    int ncol0 = nt * 128;

    // A staging: 512 chunks of 16B (1/thread), pair-line XOR pre-swizzle.
    const unsigned short* asrc;
    int coff;
    {
        int c = t;
        int line = c >> 3, p = c & 7, q = p ^ (line & 7);
        int row = line * 2 + (q >> 2), s = q & 3;
        asrc = hidb + (size_t)(brow + row) * HH + s * 8;
        coff = c * 16;
    }

    auto stageA = [&](int ks, int b) {
        __builtin_amdgcn_global_load_lds(
            (const __attribute__((address_space(1))) void*)(asrc + ks * 32),
            (__attribute__((address_space(3))) void*)(ldsA + b * 8192 + coff),
            16, 0, 0);
    };

    // W direct: per-lane base; bf[nf] at + nf*16*32; ks step = 32768 bf16.
    const unsigned short* wlane = Wt2 + ((size_t)e << 20)
                                + (size_t)(ncol0 + wn * 64 + l15) * 32 + g * 8;

    bhalf8 bf[4], bfp[4];
    auto loadW = [&](int ks, bhalf8* dst) {
        const unsigned short* p = wlane + (size_t)ks * 32768;
#pragma unroll
        for (int nf = 0; nf < 4; ++nf)
            dst[nf] = *reinterpret_cast<const bhalf8*>(p + nf * 512);
    };

    f32x4 acc[2][4] = {};

    // prologue: 3 A-stages in flight; W(0) to regs; wait for A(0)
    stageA(0, 0); stageA(1, 1); stageA(2, 2);
    loadW(0, bf);
    asm volatile("s_waitcnt vmcnt(6)" ::: "memory");
    __builtin_amdgcn_s_barrier();

    for (int ks = 0; ks < 32; ++ks) {
        const char* Af = ldsA + (ks & 3) * 8192;
        bhalf8 af[2];
#pragma unroll
        for (int mf = 0; mf < 2; ++mf) {
            int r = wm * 32 + mf * 16 + l15;
            int line = r >> 1;
            int p = (g + ((r & 1) << 2)) ^ (line & 7);
            af[mf] = *reinterpret_cast<const bhalf8*>(Af + line * 128 + p * 16);
        }
        if (ks <= 30) loadW(ks + 1, bfp);     // W prefetch for next iter
        if (ks <= 28) stageA(ks + 3, (ks + 3) & 3);
        __builtin_amdgcn_s_barrier();
        __builtin_amdgcn_s_setprio(1);
#pragma unroll
        for (int mf = 0; mf < 2; ++mf)
#pragma unroll
            for (int nf = 0; nf < 4; ++nf)
                acc[mf][nf] = __builtin_amdgcn_mfma_f32_16x16x32_bf16(
                    af[mf], bf[nf], acc[mf][nf], 0, 0, 0);
        __builtin_amdgcn_s_setprio(0);
#pragma unroll
        for (int nf = 0; nf < 4; ++nf) bf[nf] = bfp[nf];
        if (ks < 29)       { asm volatile("s_waitcnt vmcnt(6)" ::: "memory"); }
        else if (ks == 29) { asm volatile("s_waitcnt vmcnt(5)" ::: "memory"); }
        else if (ks == 30) { asm volatile("s_waitcnt vmcnt(4)" ::: "memory"); }
        __builtin_amdgcn_s_barrier();
    }

    // ---- epilogue: store y as bf16 ----
#pragma unroll
    for (int nf = 0; nf < 4; ++nf) {
        int dcol = ncol0 + wn * 64 + nf * 16 + l15;
#pragma unroll
        for (int mf = 0; mf < 2; ++mf)
#pragma unroll
            for (int j = 0; j < 4; ++j) {
                int srow = brow + wm * 32 + mf * 16 + g * 4 + j;
                ybuf[(size_t)srow * HH + dcol] = bf16u(acc[mf][nf][j]);
            }
    }
}

// ---------------------------------------------------------------------------
// Post: x = y(bf16) + bias[e] + inp; LayerNorm(x) -> d_out (f32).
// One block per row, single pass, no atomics. XCD-matched row permutation.
// ---------------------------------------------------------------------------
__global__ __launch_bounds__(256)
void post_kernel(const unsigned short* __restrict__ ybuf,
                 const float* __restrict__ inp,
                 const int* __restrict__ eidx, const float* __restrict__ bias,
                 const float* __restrict__ gamma, const float* __restrict__ beta,
                 float* __restrict__ out)
{
    int bid = blockIdx.x;
    int row = ((bid & 7) << 10) | (bid >> 3);   // XCD-matched (8192 = 8*1024)
    int bt = row >> 9;
    int e = eidx[bt];
    int t = threadIdx.x;

    size_t base = (size_t)row * HH + t * 4;
    ushort4 yv = *reinterpret_cast<const ushort4*>(&ybuf[base]);
    float4 iv = *reinterpret_cast<const float4*>(&inp[base]);
    float4 bv = *reinterpret_cast<const float4*>(&bias[e * HH + t * 4]);
    float4 x;
    x.x = ubf16(yv.x) + iv.x + bv.x;
    x.y = ubf16(yv.y) + iv.y + bv.y;
    x.z = ubf16(yv.z) + iv.z + bv.z;
    x.w = ubf16(yv.w) + iv.w + bv.w;

    float s1 = x.x + x.y + x.z + x.w;
    float s2 = x.x * x.x + x.y * x.y + x.z * x.z + x.w * x.w;
#pragma unroll
    for (int off = 32; off > 0; off >>= 1) {
        s1 += __shfl_xor(s1, off, 64);
        s2 += __shfl_xor(s2, off, 64);
    }
    __shared__ float red[8];
    if ((t & 63) == 0) { red[(t >> 6) * 2] = s1; red[(t >> 6) * 2 + 1] = s2; }
    __syncthreads();
    float S1 = red[0] + red[2] + red[4] + red[6];
    float S2 = red[1] + red[3] + red[5] + red[7];
    float mu  = S1 * (1.0f / HH);
    float var = S2 * (1.0f / HH) - mu * mu;
    float rs = rsqrtf(var + 1e-12f);

    float4 gv = *reinterpret_cast<const float4*>(&gamma[t * 4]);
    float4 be = *reinterpret_cast<const float4*>(&beta[t * 4]);
    float4 o;
    o.x = (x.x - mu) * rs * gv.x + be.x;
    o.y = (x.y - mu) * rs * gv.y + be.y;
    o.z = (x.z - mu) * rs * gv.z + be.z;
    o.w = (x.w - mu) * rs * gv.w + be.w;
    *reinterpret_cast<float4*>(&out[base]) = o;
}

extern "C" void kernel_launch(void* const* d_in, const int* in_sizes, int n_in,
                              void* d_out, int out_size, void* d_ws, size_t ws_size,
                              hipStream_t stream) {
    const float* hid   = (const float*)d_in[0];
    const float* inp   = (const float*)d_in[1];
    const int*   eidx  = (const int*)d_in[2];
    const float* W     = (const float*)d_in[3];
    const float* bias  = (const float*)d_in[4];
    const float* gamma = (const float*)d_in[5];
    const float* beta  = (const float*)d_in[6];
    float* out = (float*)d_out;

    unsigned short* Wt2  = (unsigned short*)d_ws;                        // 16 MiB
    unsigned short* hidb = (unsigned short*)((char*)d_ws + (16u << 20)); // 16 MiB
    unsigned short* ybuf = (unsigned short*)((char*)d_ws + (32u << 20)); // 16 MiB

    prep_kernel<<<6144, 256, 0, stream>>>(W, hid, eidx, Wt2, hidb);
    gemm8_kernel<<<512, 512, 0, stream>>>(hidb, eidx, Wt2, ybuf);
    post_kernel<<<BB * SS, 256, 0, stream>>>(ybuf, inp, eidx, bias, gamma, beta, out);
}

// Round 18
// 63.018 us; speedup vs baseline: 1.1253x; 1.1253x over previous
//
#include <hip/hip_runtime.h>
#include <hip/hip_bf16.h>

#define BB 16
#define SS 512
#define HH 1024

typedef __attribute__((ext_vector_type(4))) float f32x4;
typedef __attribute__((ext_vector_type(8))) short bhalf8;

static __device__ __forceinline__ unsigned int pack2(float a, float b) {
    __hip_bfloat162 h = __float22bfloat162_rn(make_float2(a, b));
    union { __hip_bfloat162 h; unsigned int u; } cv;
    cv.h = h;
    return cv.u;
}

static __device__ __forceinline__ unsigned short bf16u(float f) {
    union { float f; unsigned int u; } c; c.f = f;
    unsigned int r = c.u + 0x7FFFu + ((c.u >> 16) & 1u);   // RNE
    return (unsigned short)(r >> 16);
}

static __device__ __forceinline__ float ubf16(unsigned short u) {
    union { unsigned int u; float f; } c; c.u = ((unsigned int)u) << 16;
    return c.f;
}

// ---------------------------------------------------------------------------
// Prepass (all coalesced), identical to R16:
//   blocks [0,2048):    W[e][k][d] -> Wt[e][d][k] bf16 via LDS transpose
//   blocks [2048,6144): hid f32 -> hidb bf16
// ---------------------------------------------------------------------------
__global__ __launch_bounds__(256)
void prep_kernel(const float* __restrict__ W, const float* __restrict__ hid,
                 const int* __restrict__ eidx, unsigned short* __restrict__ Wt,
                 unsigned short* __restrict__ hidb)
{
    int bid = blockIdx.x;
    int t = threadIdx.x;
    if (bid < 2048) {
        __shared__ float lds[32 * 132];
        int e  = bid >> 8;
        bool used = false;
        for (int b = 0; b < BB; ++b) used = used || (eidx[b] == e);
        if (!used) return;
        int rem = bid & 255;
        int kt = rem >> 3, dt = rem & 7;     // 32-k x 128-d tile
#pragma unroll
        for (int i = 0; i < 4; ++i) {
            int idx = t + i * 256;
            int row = idx >> 5, col4 = idx & 31;
            float4 v = *(const float4*)(W + ((size_t)e << 20)
                        + (size_t)(kt * 32 + row) * HH + dt * 128 + col4 * 4);
            float* dst = &lds[row * 132 + col4 * 4];
            dst[0] = v.x; dst[1] = v.y; dst[2] = v.z; dst[3] = v.w;
        }
        __syncthreads();
        int d = t >> 1, kh = t & 1;
        unsigned int u[8];
#pragma unroll
        for (int p = 0; p < 8; ++p) {
            float a = lds[(kh * 16 + p * 2)     * 132 + d];
            float b = lds[(kh * 16 + p * 2 + 1) * 132 + d];
            u[p] = pack2(a, b);
        }
        unsigned short* dst = Wt + ((size_t)e << 20)
                            + (size_t)(dt * 128 + d) * HH + kt * 32 + kh * 16;
        *reinterpret_cast<uint4*>(dst)     = make_uint4(u[0], u[1], u[2], u[3]);
        *reinterpret_cast<uint4*>(dst + 8) = make_uint4(u[4], u[5], u[6], u[7]);
    } else {
        int bid2 = bid - 2048;               // 2 rows per block
        int r = bid2 * 2 + (t >> 7);
        int col = (t & 127) * 8;
        const float* src = hid + (size_t)r * HH + col;
        float4 v0 = *(const float4*)(src);
        float4 v1 = *(const float4*)(src + 4);
        uint4 o;
        o.x = pack2(v0.x, v0.y); o.y = pack2(v0.z, v0.w);
        o.z = pack2(v1.x, v1.y); o.w = pack2(v1.z, v1.w);
        *reinterpret_cast<uint4*>(hidb + (size_t)r * HH + col) = o;
    }
}

// ---------------------------------------------------------------------------
// PURE GEMM, m97-structure at high block-level parallelism:
// y = hid @ W[e] (bf16 store). 1024 blocks x 256 thr (4 waves, 2m x 2n of
// 64x32), tile 128x64, BK=32, DOUBLE-buffered LDS (24KB -> ~5 blocks/CU,
// ~20 waves/CU). Plain __syncthreads per K-step (full drain) — the drain of
// one block is covered by the 4 other resident blocks' MFMA phases.
// pair-line XOR LDS layout (verified 0 conflicts), mfma 16x16x32 bf16.
// ---------------------------------------------------------------------------
__global__ __launch_bounds__(256, 5)
void gemm8_kernel(const unsigned short* __restrict__ hidb,
                  const int* __restrict__ eidx,
                  const unsigned short* __restrict__ Wt,
                  unsigned short* __restrict__ ybuf)
{
    __shared__ char ldsA[2 * 8192];    // A: bf16 [128 r][32 k] per buf
    __shared__ char ldsW[2 * 4096];    // W: bf16 [64 d][32 k] per buf

    int bx  = blockIdx.x;
    int swz = (bx & 7) * 128 + (bx >> 3);     // XCD-bijective (1024 % 8 == 0)
    int bt   = swz >> 6;                      // batch 0..15
    int rem  = swz & 63;
    int mt = rem >> 4, nt = rem & 15;         // 4 m-tiles x 16 n-tiles
    int e = eidx[bt];

    int t = threadIdx.x, wave = t >> 6, lane = t & 63;
    int l15 = lane & 15, g = lane >> 4;
    int wm = wave >> 1, wn = wave & 1;        // 2m x 2n, wave tile 64x32

    int brow = bt * SS + mt * 128;
    int ncol0 = nt * 64;

    // A: 512 chunks of 16B (2/thread); W: 256 chunks (1/thread).
    // chunk c: line=c>>3, p=c&7, q=p^(line&7), row=2*line+(q>>2), s=q&3.
    const unsigned short* asrc[2];
    int aoff[2];
#pragma unroll
    for (int i = 0; i < 2; ++i) {
        int c = t + i * 256;
        int line = c >> 3, p = c & 7, q = p ^ (line & 7);
        int row = line * 2 + (q >> 2), s = q & 3;
        asrc[i] = hidb + (size_t)(brow + row) * HH + s * 8;
        aoff[i] = c * 16;
    }
    const unsigned short* wsrc;
    int woff;
    {
        int c = t;
        int line = c >> 3, p = c & 7, q = p ^ (line & 7);
        int row = line * 2 + (q >> 2), s = q & 3;
        wsrc = Wt + ((size_t)e << 20) + (size_t)(ncol0 + row) * HH + s * 8;
        woff = c * 16;
    }

    auto stage = [&](int ks, int sel) {
#pragma unroll
        for (int i = 0; i < 2; ++i)
            __builtin_amdgcn_global_load_lds(
                (const __attribute__((address_space(1))) void*)(asrc[i] + ks * 32),
                (__attribute__((address_space(3))) void*)(ldsA + sel * 8192 + aoff[i]),
                16, 0, 0);
        __builtin_amdgcn_global_load_lds(
            (const __attribute__((address_space(1))) void*)(wsrc + ks * 32),
            (__attribute__((address_space(3))) void*)(ldsW + sel * 4096 + woff),
            16, 0, 0);
    };

    f32x4 acc[4][2] = {};

    // prologue
    stage(0, 0);
    __syncthreads();

    for (int ks = 0; ks < 32; ++ks) {
        int sel = ks & 1;
        if (ks < 31) stage(ks + 1, sel ^ 1);   // issue-early; drained by barrier

        const char* Af = ldsA + sel * 8192;
        const char* Wf = ldsW + sel * 4096;
        bhalf8 af[4], bf[2];
#pragma unroll
        for (int mf = 0; mf < 4; ++mf) {
            int r = wm * 64 + mf * 16 + l15;
            int line = r >> 1;
            int p = (g + ((r & 1) << 2)) ^ (line & 7);
            af[mf] = *reinterpret_cast<const bhalf8*>(Af + line * 128 + p * 16);
        }
#pragma unroll
        for (int nf = 0; nf < 2; ++nf) {
            int d = wn * 32 + nf * 16 + l15;
            int line = d >> 1;
            int p = (g + ((d & 1) << 2)) ^ (line & 7);
            bf[nf] = *reinterpret_cast<const bhalf8*>(Wf + line * 128 + p * 16);
        }
        __builtin_amdgcn_s_setprio(1);
#pragma unroll
        for (int mf = 0; mf < 4; ++mf)
#pragma unroll
            for (int nf = 0; nf < 2; ++nf)
                acc[mf][nf] = __builtin_amdgcn_mfma_f32_16x16x32_bf16(
                    af[mf], bf[nf], acc[mf][nf], 0, 0, 0);
        __builtin_amdgcn_s_setprio(0);
        __syncthreads();                        // drains vmcnt+lgkm; other
                                                // resident blocks cover it
    }

    // ---- epilogue: store y as bf16 ----
#pragma unroll
    for (int nf = 0; nf < 2; ++nf) {
        int dcol = ncol0 + wn * 32 + nf * 16 + l15;
#pragma unroll
        for (int mf = 0; mf < 4; ++mf)
#pragma unroll
            for (int j = 0; j < 4; ++j) {
                int srow = brow + wm * 64 + mf * 16 + g * 4 + j;
                ybuf[(size_t)srow * HH + dcol] = bf16u(acc[mf][nf][j]);
            }
    }
}

// ---------------------------------------------------------------------------
// Post: x = y(bf16) + bias[e] + inp; LayerNorm(x) -> d_out (f32).
// One block per row, single pass, no atomics. XCD-matched row permutation.
// ---------------------------------------------------------------------------
__global__ __launch_bounds__(256)
void post_kernel(const unsigned short* __restrict__ ybuf,
                 const float* __restrict__ inp,
                 const int* __restrict__ eidx, const float* __restrict__ bias,
                 const float* __restrict__ gamma, const float* __restrict__ beta,
                 float* __restrict__ out)
{
    int bid = blockIdx.x;
    int row = ((bid & 7) << 10) | (bid >> 3);   // XCD-matched (8192 = 8*1024)
    int bt = row >> 9;
    int e = eidx[bt];
    int t = threadIdx.x;

    size_t base = (size_t)row * HH + t * 4;
    ushort4 yv = *reinterpret_cast<const ushort4*>(&ybuf[base]);
    float4 iv = *reinterpret_cast<const float4*>(&inp[base]);
    float4 bv = *reinterpret_cast<const float4*>(&bias[e * HH + t * 4]);
    float4 x;
    x.x = ubf16(yv.x) + iv.x + bv.x;
    x.y = ubf16(yv.y) + iv.y + bv.y;
    x.z = ubf16(yv.z) + iv.z + bv.z;
    x.w = ubf16(yv.w) + iv.w + bv.w;

    float s1 = x.x + x.y + x.z + x.w;
    float s2 = x.x * x.x + x.y * x.y + x.z * x.z + x.w * x.w;
#pragma unroll
    for (int off = 32; off > 0; off >>= 1) {
        s1 += __shfl_xor(s1, off, 64);
        s2 += __shfl_xor(s2, off, 64);
    }
    __shared__ float red[8];
    if ((t & 63) == 0) { red[(t >> 6) * 2] = s1; red[(t >> 6) * 2 + 1] = s2; }
    __syncthreads();
    float S1 = red[0] + red[2] + red[4] + red[6];
    float S2 = red[1] + red[3] + red[5] + red[7];
    float mu  = S1 * (1.0f / HH);
    float var = S2 * (1.0f / HH) - mu * mu;
    float rs = rsqrtf(var + 1e-12f);

    float4 gv = *reinterpret_cast<const float4*>(&gamma[t * 4]);
    float4 be = *reinterpret_cast<const float4*>(&beta[t * 4]);
    float4 o;
    o.x = (x.x - mu) * rs * gv.x + be.x;
    o.y = (x.y - mu) * rs * gv.y + be.y;
    o.z = (x.z - mu) * rs * gv.z + be.z;
    o.w = (x.w - mu) * rs * gv.w + be.w;
    *reinterpret_cast<float4*>(&out[base]) = o;
}

extern "C" void kernel_launch(void* const* d_in, const int* in_sizes, int n_in,
                              void* d_out, int out_size, void* d_ws, size_t ws_size,
                              hipStream_t stream) {
    const float* hid   = (const float*)d_in[0];
    const float* inp   = (const float*)d_in[1];
    const int*   eidx  = (const int*)d_in[2];
    const float* W     = (const float*)d_in[3];
    const float* bias  = (const float*)d_in[4];
    const float* gamma = (const float*)d_in[5];
    const float* beta  = (const float*)d_in[6];
    float* out = (float*)d_out;

    unsigned short* Wt   = (unsigned short*)d_ws;                        // 16 MiB
    unsigned short* hidb = (unsigned short*)((char*)d_ws + (16u << 20)); // 16 MiB
    unsigned short* ybuf = (unsigned short*)((char*)d_ws + (32u << 20)); // 16 MiB

    prep_kernel<<<6144, 256, 0, stream>>>(W, hid, eidx, Wt, hidb);
    gemm8_kernel<<<1024, 256, 0, stream>>>(hidb, eidx, Wt, ybuf);
    post_kernel<<<BB * SS, 256, 0, stream>>>(ybuf, inp, eidx, bias, gamma, beta, out);
}

// Round 19
// 56.318 us; speedup vs baseline: 1.2592x; 1.1190x over previous
//
#include <hip/hip_runtime.h>
#include <hip/hip_bf16.h>

#define BB 16
#define SS 512
#define HH 1024

typedef __attribute__((ext_vector_type(4))) float f32x4;
typedef __attribute__((ext_vector_type(8))) short bhalf8;

static __device__ __forceinline__ unsigned int pack2(float a, float b) {
    __hip_bfloat162 h = __float22bfloat162_rn(make_float2(a, b));
    union { __hip_bfloat162 h; unsigned int u; } cv;
    cv.h = h;
    return cv.u;
}

static __device__ __forceinline__ unsigned short bf16u(float f) {
    union { float f; unsigned int u; } c; c.f = f;
    unsigned int r = c.u + 0x7FFFu + ((c.u >> 16) & 1u);   // RNE
    return (unsigned short)(r >> 16);
}

static __device__ __forceinline__ float ubf16(unsigned short u) {
    union { unsigned int u; float f; } c; c.u = ((unsigned int)u) << 16;
    return c.f;
}

// ---------------------------------------------------------------------------
// Prepass (all coalesced):
//   blocks [0,2048):    W[e][k][d] -> Wt[e][d][k] bf16 via LDS transpose
//   blocks [2048,6144): hid f32 -> hidb bf16
// ---------------------------------------------------------------------------
__global__ __launch_bounds__(256)
void prep_kernel(const float* __restrict__ W, const float* __restrict__ hid,
                 const int* __restrict__ eidx, unsigned short* __restrict__ Wt,
                 unsigned short* __restrict__ hidb)
{
    int bid = blockIdx.x;
    int t = threadIdx.x;
    if (bid < 2048) {
        __shared__ float lds[32 * 132];
        int e  = bid >> 8;
        bool used = false;
        for (int b = 0; b < BB; ++b) used = used || (eidx[b] == e);
        if (!used) return;
        int rem = bid & 255;
        int kt = rem >> 3, dt = rem & 7;     // 32-k x 128-d tile
#pragma unroll
        for (int i = 0; i < 4; ++i) {
            int idx = t + i * 256;
            int row = idx >> 5, col4 = idx & 31;
            float4 v = *(const float4*)(W + ((size_t)e << 20)
                        + (size_t)(kt * 32 + row) * HH + dt * 128 + col4 * 4);
            float* dst = &lds[row * 132 + col4 * 4];
            dst[0] = v.x; dst[1] = v.y; dst[2] = v.z; dst[3] = v.w;
        }
        __syncthreads();
        int d = t >> 1, kh = t & 1;
        unsigned int u[8];
#pragma unroll
        for (int p = 0; p < 8; ++p) {
            float a = lds[(kh * 16 + p * 2)     * 132 + d];
            float b = lds[(kh * 16 + p * 2 + 1) * 132 + d];
            u[p] = pack2(a, b);
        }
        unsigned short* dst = Wt + ((size_t)e << 20)
                            + (size_t)(dt * 128 + d) * HH + kt * 32 + kh * 16;
        *reinterpret_cast<uint4*>(dst)     = make_uint4(u[0], u[1], u[2], u[3]);
        *reinterpret_cast<uint4*>(dst + 8) = make_uint4(u[4], u[5], u[6], u[7]);
    } else {
        int bid2 = bid - 2048;               // 2 rows per block
        int r = bid2 * 2 + (t >> 7);
        int col = (t & 127) * 8;
        const float* src = hid + (size_t)r * HH + col;
        float4 v0 = *(const float4*)(src);
        float4 v1 = *(const float4*)(src + 4);
        uint4 o;
        o.x = pack2(v0.x, v0.y); o.y = pack2(v0.z, v0.w);
        o.z = pack2(v1.x, v1.y); o.w = pack2(v1.z, v1.w);
        *reinterpret_cast<uint4*>(hidb + (size_t)r * HH + col) = o;
    }
}

// ---------------------------------------------------------------------------
// PURE GEMM (session-best configuration): y = hid @ W[e], bf16 store.
// 512 blocks x 512 thr (8 waves, 4m x 2n of 32x64), tile 128x128, BK=32,
// quad-buffered LDS (64KB -> 2 resident blocks/CU = 16 waves/CU).
// Per iter {6 ds_read; stage(ks+3) 2 loads; s_barrier; setprio+8 MFMA;
// s_waitcnt vmcnt(4); s_barrier}  (counted drain only in tail).
// pair-line XOR LDS layout (verified 0 conflicts), mfma 16x16x32 bf16.
// ---------------------------------------------------------------------------
__global__ __launch_bounds__(512, 4)
void gemm8_kernel(const unsigned short* __restrict__ hidb,
                  const int* __restrict__ eidx,
                  const unsigned short* __restrict__ Wt,
                  unsigned short* __restrict__ ybuf)
{
    __shared__ char ldsA[4 * 8192];    // A: bf16 [128 r][32 k] per buf
    __shared__ char ldsW[4 * 8192];    // W: bf16 [128 d][32 k] per buf

    int bx  = blockIdx.x;
    int swz = (bx & 7) * 64 + (bx >> 3);      // XCD-bijective (512 % 8 == 0)
    int bt   = swz >> 5;                      // batch 0..15
    int tile = swz & 31;
    int mt = tile >> 3, nt = tile & 7;        // 4 m-tiles x 8 n-tiles
    int e = eidx[bt];

    int t = threadIdx.x, wave = t >> 6, lane = t & 63;
    int l15 = lane & 15, g = lane >> 4;
    int wm = wave >> 1, wn = wave & 1;        // 4m x 2n, wave tile 32x64

    int brow = bt * SS + mt * 128;
    int ncol0 = nt * 128;

    // A: 512 chunks of 16B (1/thread); W: 512 chunks (1/thread).
    // chunk c: line=c>>3, p=c&7, q=p^(line&7), row=2*line+(q>>2), s=q&3.
    const unsigned short* asrc;
    const unsigned short* wsrc;
    int coff;
    {
        int c = t;
        int line = c >> 3, p = c & 7, q = p ^ (line & 7);
        int row = line * 2 + (q >> 2), s = q & 3;
        asrc = hidb + (size_t)(brow + row) * HH + s * 8;
        wsrc = Wt + ((size_t)e << 20) + (size_t)(ncol0 + row) * HH + s * 8;
        coff = c * 16;
    }

    auto stage = [&](int ks, int b) {
        __builtin_amdgcn_global_load_lds(
            (const __attribute__((address_space(1))) void*)(asrc + ks * 32),
            (__attribute__((address_space(3))) void*)(ldsA + b * 8192 + coff),
            16, 0, 0);
        __builtin_amdgcn_global_load_lds(
            (const __attribute__((address_space(1))) void*)(wsrc + ks * 32),
            (__attribute__((address_space(3))) void*)(ldsW + b * 8192 + coff),
            16, 0, 0);
    };

    f32x4 acc[2][4] = {};

    auto body = [&](int ks, bool do_stage) {
        const char* Af = ldsA + (ks & 3) * 8192;
        const char* Wf = ldsW + (ks & 3) * 8192;
        bhalf8 af[2], bf[4];
#pragma unroll
        for (int mf = 0; mf < 2; ++mf) {
            int r = wm * 32 + mf * 16 + l15;
            int line = r >> 1;
            int p = (g + ((r & 1) << 2)) ^ (line & 7);
            af[mf] = *reinterpret_cast<const bhalf8*>(Af + line * 128 + p * 16);
        }
#pragma unroll
        for (int nf = 0; nf < 4; ++nf) {
            int d = wn * 64 + nf * 16 + l15;
            int line = d >> 1;
            int p = (g + ((d & 1) << 2)) ^ (line & 7);
            bf[nf] = *reinterpret_cast<const bhalf8*>(Wf + line * 128 + p * 16);
        }
        if (do_stage) stage(ks + 3, (ks + 3) & 3);
        __builtin_amdgcn_s_barrier();
        __builtin_amdgcn_s_setprio(1);
#pragma unroll
        for (int mf = 0; mf < 2; ++mf)
#pragma unroll
            for (int nf = 0; nf < 4; ++nf)
                acc[mf][nf] = __builtin_amdgcn_mfma_f32_16x16x32_bf16(
                    af[mf], bf[nf], acc[mf][nf], 0, 0, 0);
        __builtin_amdgcn_s_setprio(0);
    };

    // prologue: 3 stages in flight (6 loads), wait for the first (4 remain)
    stage(0, 0); stage(1, 1); stage(2, 2);
    asm volatile("s_waitcnt vmcnt(4)" ::: "memory");
    __builtin_amdgcn_s_barrier();

    for (int ks = 0; ks < 29; ++ks) {
        body(ks, true);
        asm volatile("s_waitcnt vmcnt(4)" ::: "memory");
        __builtin_amdgcn_s_barrier();
    }
    body(29, false);
    asm volatile("s_waitcnt vmcnt(2)" ::: "memory");
    __builtin_amdgcn_s_barrier();
    body(30, false);
    asm volatile("s_waitcnt vmcnt(0)" ::: "memory");
    __builtin_amdgcn_s_barrier();
    body(31, false);

    // ---- epilogue: store y as bf16 ----
#pragma unroll
    for (int nf = 0; nf < 4; ++nf) {
        int dcol = ncol0 + wn * 64 + nf * 16 + l15;
#pragma unroll
        for (int mf = 0; mf < 2; ++mf)
#pragma unroll
            for (int j = 0; j < 4; ++j) {
                int srow = brow + wm * 32 + mf * 16 + g * 4 + j;
                ybuf[(size_t)srow * HH + dcol] = bf16u(acc[mf][nf][j]);
            }
    }
}

// ---------------------------------------------------------------------------
// Post: x = y(bf16) + bias[e] + inp; LayerNorm(x) -> d_out (f32).
// One block per row, single pass, no atomics. XCD-matched row permutation.
// ---------------------------------------------------------------------------
__global__ __launch_bounds__(256)
void post_kernel(const unsigned short* __restrict__ ybuf,
                 const float* __restrict__ inp,
                 const int* __restrict__ eidx, const float* __restrict__ bias,
                 const float* __restrict__ gamma, const float* __restrict__ beta,
                 float* __restrict__ out)
{
    int bid = blockIdx.x;
    int row = ((bid & 7) << 10) | (bid >> 3);   // XCD-matched (8192 = 8*1024)
    int bt = row >> 9;
    int e = eidx[bt];
    int t = threadIdx.x;

    size_t base = (size_t)row * HH + t * 4;
    ushort4 yv = *reinterpret_cast<const ushort4*>(&ybuf[base]);
    float4 iv = *reinterpret_cast<const float4*>(&inp[base]);
    float4 bv = *reinterpret_cast<const float4*>(&bias[e * HH + t * 4]);
    float4 x;
    x.x = ubf16(yv.x) + iv.x + bv.x;
    x.y = ubf16(yv.y) + iv.y + bv.y;
    x.z = ubf16(yv.z) + iv.z + bv.z;
    x.w = ubf16(yv.w) + iv.w + bv.w;

    float s1 = x.x + x.y + x.z + x.w;
    float s2 = x.x * x.x + x.y * x.y + x.z * x.z + x.w * x.w;
#pragma unroll
    for (int off = 32; off > 0; off >>= 1) {
        s1 += __shfl_xor(s1, off, 64);
        s2 += __shfl_xor(s2, off, 64);
    }
    __shared__ float red[8];
    if ((t & 63) == 0) { red[(t >> 6) * 2] = s1; red[(t >> 6) * 2 + 1] = s2; }
    __syncthreads();
    float S1 = red[0] + red[2] + red[4] + red[6];
    float S2 = red[1] + red[3] + red[5] + red[7];
    float mu  = S1 * (1.0f / HH);
    float var = S2 * (1.0f / HH) - mu * mu;
    float rs = rsqrtf(var + 1e-12f);

    float4 gv = *reinterpret_cast<const float4*>(&gamma[t * 4]);
    float4 be = *reinterpret_cast<const float4*>(&beta[t * 4]);
    float4 o;
    o.x = (x.x - mu) * rs * gv.x + be.x;
    o.y = (x.y - mu) * rs * gv.y + be.y;
    o.z = (x.z - mu) * rs * gv.z + be.z;
    o.w = (x.w - mu) * rs * gv.w + be.w;
    *reinterpret_cast<float4*>(&out[base]) = o;
}

extern "C" void kernel_launch(void* const* d_in, const int* in_sizes, int n_in,
                              void* d_out, int out_size, void* d_ws, size_t ws_size,
                              hipStream_t stream) {
    const float* hid   = (const float*)d_in[0];
    const float* inp   = (const float*)d_in[1];
    const int*   eidx  = (const int*)d_in[2];
    const float* W     = (const float*)d_in[3];
    const float* bias  = (const float*)d_in[4];
    const float* gamma = (const float*)d_in[5];
    const float* beta  = (const float*)d_in[6];
    float* out = (float*)d_out;

    unsigned short* Wt   = (unsigned short*)d_ws;                        // 16 MiB
    unsigned short* hidb = (unsigned short*)((char*)d_ws + (16u << 20)); // 16 MiB
    unsigned short* ybuf = (unsigned short*)((char*)d_ws + (32u << 20)); // 16 MiB

    prep_kernel<<<6144, 256, 0, stream>>>(W, hid, eidx, Wt, hidb);
    gemm8_kernel<<<512, 512, 0, stream>>>(hidb, eidx, Wt, ybuf);
    post_kernel<<<BB * SS, 256, 0, stream>>>(ybuf, inp, eidx, bias, gamma, beta, out);
}